// Round 6
// baseline (10336.697 us; speedup 1.0000x reference)
//
#include <hip/hip_runtime.h>
#include <hip/hip_bf16.h>

// ---------------------------------------------------------------------------
// BasicDGCNN forward, MI355X (gfx950). Inputs f32, OUTPUT f32 (round-5
// diagnosis: error 54.05 == my gfeat packed into the f32 vertex window ->
// output buffer is float32; the test's "(bf16" label is hardcoded).
// Output layout (f32 elements, flat):
//   [0,768) vertex | [768,772) num_vertices | [772,776) nvs |
//   [776,1800) gfeat | [1800,7341832) x_concat [4,8192,224]=[x1|x2|x3]
//
// x1/x2/x3 live only in the f32 x_concat region of d_out; layers 2/3 read
// features back from there (lossless). ws need = 1,310,720 B (idx; part/gft
// alias idx after it is dead) — proven safe in rounds 3-5.
// ---------------------------------------------------------------------------

#define NPTS 8192
#define BATCH 4
#define KNBR 20

// --------------------------- KNN (top-21, drop first) ----------------------
// Thread = query point; 128-pt j-tiles staged in LDS; norms in-kernel.
// dist = xx_i + xx_j - 2*dot. Sorted top-21, ties keep earlier j (== jax
// top_k of -dist, stable); entry 0 dropped (self / idx[:,:,1:]).
template <int D, int RS>
__global__ __launch_bounds__(128) void knn_kernel(
    const float* feat, unsigned short* __restrict__ idxout) {
    const int TJ = 128;
    __shared__ float xj[TJ * D];
    __shared__ float xxj[TJ];

    int gi = blockIdx.x * 128 + threadIdx.x;     // global row
    int b  = gi >> 13;
    int ib = gi & (NPTS - 1);
    const float* fb = feat + (size_t)b * NPTS * RS;

    float xi[D];
    float xxi = 0.f;
    #pragma unroll
    for (int c = 0; c < D; ++c) {
        xi[c] = fb[(size_t)ib * RS + c];
        xxi = fmaf(xi[c], xi[c], xxi);
    }

    float dl[21];
    int   il[21];
    #pragma unroll
    for (int t = 0; t < 21; ++t) { dl[t] = __builtin_inff(); il[t] = 0; }

    for (int j0 = 0; j0 < NPTS; j0 += TJ) {
        __syncthreads();                          // protect prior-iter reads
        for (int t = threadIdx.x; t < TJ * D; t += 128) {
            int r = t / D, c = t - r * D;
            xj[t] = fb[(size_t)(j0 + r) * RS + c];
        }
        __syncthreads();
        {
            int t = threadIdx.x;
            float s = 0.f;
            #pragma unroll
            for (int c = 0; c < D; ++c) s = fmaf(xj[t * D + c], xj[t * D + c], s);
            xxj[t] = s;
        }
        __syncthreads();
        for (int jj = 0; jj < TJ; ++jj) {
            float dot = 0.f;
            #pragma unroll
            for (int c = 0; c < D; ++c) dot = fmaf(xi[c], xj[jj * D + c], dot);
            float d = xxi + xxj[jj] - 2.0f * dot;
            if (d < dl[20]) {               // strict: equal dist keeps earlier j
                dl[20] = d; il[20] = j0 + jj;
                #pragma unroll
                for (int t = 20; t > 0; --t) {
                    if (dl[t] < dl[t - 1]) {
                        float td = dl[t]; dl[t] = dl[t - 1]; dl[t - 1] = td;
                        int   ti = il[t]; il[t] = il[t - 1]; il[t - 1] = ti;
                    }
                }
            }
        }
    }
    unsigned short* op = idxout + (size_t)gi * KNBR;
    #pragma unroll
    for (int t = 1; t < 21; ++t) op[t - 1] = (unsigned short)il[t];
}

// --------------------------- EdgeConv (fused BN+leaky+max_k) ---------------
// o-tiled via blockIdx.y; weights in LDS, odd row stride (2C+1). feat/outb
// may point into the same x_concat buffer but touch DISJOINT channel ranges
// ([0,CIN) read vs [concat_off,concat_off+COUT) write) -> no __restrict__.
template <int CIN, int RS, int COUT, int OTILE>
__global__ __launch_bounds__(256) void edgeconv_kernel(
    const float* feat, const unsigned short* __restrict__ knn,
    const float* __restrict__ W, const float* __restrict__ g,
    const float* __restrict__ beta, const float* __restrict__ mu,
    const float* __restrict__ var,
    float* outb, int concat_off) {
    const int GP = 256 / OTILE;
    const int WS = 2 * CIN + 1;
    __shared__ float Wl[OTILE * WS];
    __shared__ float xil[GP][CIN];
    __shared__ float sl[OTILE], bl[OTILE], ml[OTILE];

    int tid = threadIdx.x;
    int h   = blockIdx.y;                        // out-channel tile
    for (int t = tid; t < OTILE * 2 * CIN; t += 256) {
        int r = t / (2 * CIN), c = t - r * 2 * CIN;
        Wl[r * WS + c] = W[(size_t)(h * OTILE + r) * 2 * CIN + c];
    }
    for (int t = tid; t < OTILE; t += 256) {
        int o = h * OTILE + t;
        sl[t] = g[o] * rsqrtf(var[o] + 1e-5f);
        bl[t] = beta[o];
        ml[t] = mu[o];
    }
    int n0 = blockIdx.x * GP;                    // global row base (b*N + ib)
    for (int t = tid; t < GP * CIN; t += 256) {
        int p = t / CIN, c = t - p * CIN;
        xil[p][c] = feat[(size_t)(n0 + p) * RS + c];
    }
    __syncthreads();

    int ol = tid % OTILE, p = tid / OTILE;
    int n = n0 + p;
    int b = n >> 13;
    const float* fb = feat + ((size_t)b << 13) * RS;

    float a = 0.f;                               // center dot: Wc . x_i
    #pragma unroll
    for (int c = 0; c < CIN; ++c) a = fmaf(Wl[ol * WS + c], xil[p][c], a);

    float s = sl[ol], mm = ml[ol], bb = bl[ol];
    float best = -__builtin_inff();
    const unsigned short* kp = knn + (size_t)n * KNBR;
    for (int k = 0; k < KNBR; ++k) {
        int j = ((int)kp[k]) & (NPTS - 1);       // fault-proof
        const float* xjp = fb + (size_t)j * RS;
        float acc = a;
        #pragma unroll
        for (int c = 0; c < CIN; ++c)
            acc = fmaf(Wl[ol * WS + CIN + c], xjp[c] - xil[p][c], acc);
        float y = (acc - mm) * s + bb;
        y = (y >= 0.f) ? y : 0.2f * y;
        best = fmaxf(best, y);
    }
    int o = h * OTILE + ol;
    outb[(size_t)n * 224 + concat_off + o] = best;
}

// --------------------------- conv_global + partial max over N --------------
// Zero LDS. block = (b, 64-pt chunk); thread = out-channel o (256); register
// acc[32] per 32-pt group; W row streamed from L2; feature reads wave-uniform.
__global__ __launch_bounds__(256) void convglobal_kernel(
    const float* __restrict__ xcat,
    const float* __restrict__ Wg, const float* __restrict__ gg,
    const float* __restrict__ bg, const float* __restrict__ mg,
    const float* __restrict__ vg,
    float* __restrict__ partial) {
    int o     = threadIdx.x;
    int chunk = blockIdx.x & 127;
    int b     = blockIdx.x >> 7;

    float s  = gg[o] * rsqrtf(vg[o] + 1e-5f);
    float mm = mg[o], bb = bg[o];
    const float* wrow = Wg + (size_t)o * 224;

    float best = -__builtin_inff();
    for (int grp = 0; grp < 2; ++grp) {
        int n0 = b * NPTS + chunk * 64 + grp * 32;
        float acc[32];
        #pragma unroll
        for (int p = 0; p < 32; ++p) acc[p] = 0.f;

        for (int c = 0; c < 224; ++c) {
            float w = wrow[c];
            const float* f = xcat + (size_t)n0 * 224 + c;
            #pragma unroll
            for (int p = 0; p < 32; ++p) acc[p] = fmaf(w, f[p * 224], acc[p]);
        }
        #pragma unroll
        for (int p = 0; p < 32; ++p) {
            float y = (acc[p] - mm) * s + bb;
            y = (y >= 0.f) ? y : 0.2f * y;
            best = fmaxf(best, y);
        }
    }
    partial[(size_t)blockIdx.x * 256 + o] = best;
}

__global__ void reduce_gfeat_kernel(const float* __restrict__ partial,
                                    float* __restrict__ gfeat,
                                    float* __restrict__ outg) {
    int b = blockIdx.x, o = threadIdx.x;
    float best = -__builtin_inff();
    for (int ch = 0; ch < 128; ++ch)
        best = fmaxf(best, partial[((size_t)b * 128 + ch) * 256 + o]);
    gfeat[b * 256 + o] = best;
    outg[b * 256 + o]  = best;
}

// --------------------------- heads (per-batch block) -----------------------
__global__ __launch_bounds__(256) void heads_kernel(
    const float* __restrict__ gfeat,
    const float* __restrict__ Wv1, const float* __restrict__ bv1,
    const float* __restrict__ Wv2, const float* __restrict__ bv2,
    const float* __restrict__ Wq1, const float* __restrict__ bq1,
    const float* __restrict__ Wq2, const float* __restrict__ bq2,
    float* __restrict__ out) {
    int b = blockIdx.x, t = threadIdx.x;
    __shared__ float gf[256], h[512], q[64];
    gf[t] = gfeat[b * 256 + t];
    __syncthreads();
    for (int r = t; r < 512; r += 256) {
        float acc = bv1[r];
        for (int c = 0; c < 256; ++c) acc = fmaf(Wv1[r * 256 + c], gf[c], acc);
        h[r] = fmaxf(acc, 0.f);
    }
    __syncthreads();
    if (t < 192) {
        float acc = bv2[t];
        for (int c = 0; c < 512; ++c) acc = fmaf(Wv2[t * 512 + c], h[c], acc);
        out[b * 192 + t] = acc;               // vertex_coords
    } else {
        int r = t - 192;
        if (r < 64) {
            float acc = bq1[r];
            for (int c = 0; c < 256; ++c) acc = fmaf(Wq1[r * 256 + c], gf[c], acc);
            q[r] = fmaxf(acc, 0.f);
        }
    }
    __syncthreads();
    if (t == 0) {
        float acc = bq2[0];
        for (int c = 0; c < 64; ++c) acc = fmaf(Wq2[c], q[c], acc);
        float nv = 1.0f / (1.0f + expf(-acc));
        out[772 + b] = nv;                                       // nvs
        float num = fminf(fmaxf(rintf(nv * 64.0f), 1.0f), 64.0f);
        out[768 + b] = num;                                      // num_vertices
    }
}

// --------------------------- launch --------------------------------------
extern "C" void kernel_launch(void* const* d_in, const int* in_sizes, int n_in,
                              void* d_out, int out_size, void* d_ws, size_t ws_size,
                              hipStream_t stream) {
    (void)in_sizes; (void)n_in; (void)out_size; (void)ws_size;
    const float* x   = (const float*)d_in[0];
    const float* W1  = (const float*)d_in[1];
    const float* g1  = (const float*)d_in[2];
    const float* b1  = (const float*)d_in[3];
    const float* m1  = (const float*)d_in[4];
    const float* v1  = (const float*)d_in[5];
    const float* W2  = (const float*)d_in[6];
    const float* g2  = (const float*)d_in[7];
    const float* b2  = (const float*)d_in[8];
    const float* m2  = (const float*)d_in[9];
    const float* v2  = (const float*)d_in[10];
    const float* W3  = (const float*)d_in[11];
    const float* g3  = (const float*)d_in[12];
    const float* b3  = (const float*)d_in[13];
    const float* m3  = (const float*)d_in[14];
    const float* v3  = (const float*)d_in[15];
    const float* Wg  = (const float*)d_in[16];
    const float* gg  = (const float*)d_in[17];
    const float* bg  = (const float*)d_in[18];
    const float* mg  = (const float*)d_in[19];
    const float* vg  = (const float*)d_in[20];
    const float* Wv1 = (const float*)d_in[21];
    const float* bv1 = (const float*)d_in[22];
    const float* Wv2 = (const float*)d_in[23];
    const float* bv2 = (const float*)d_in[24];
    const float* Wq1 = (const float*)d_in[25];
    const float* bq1 = (const float*)d_in[26];
    const float* Wq2 = (const float*)d_in[27];
    const float* bq2 = (const float*)d_in[28];

    float* out  = (float*)d_out;
    float* xcat = out + 1800;                    // f32 [4,8192,224]
    char* ws = (char*)d_ws;
    const int ROWS = BATCH * NPTS;   // 32768

    // ws layout (1,310,720 B total; part/gft alias idx AFTER it is dead):
    unsigned short* idx  = (unsigned short*)(ws);        // [32768,20] u16
    float*          part = (float*)(ws);                 // [512,256] f32 (alias)
    float*          gft  = (float*)(ws + 524288);        // [4,256]   f32 (alias)

    // ---- EdgeConv 1: 5 -> 32 (from f32 x; writes f32 xcat[:,0:32))
    knn_kernel<5, 5><<<ROWS / 128, 128, 0, stream>>>(x, idx);
    edgeconv_kernel<5, 5, 32, 32>
        <<<dim3(ROWS / 8, 1), 256, 0, stream>>>(x, idx, W1, g1, b1, m1, v1, xcat, 0);

    // ---- EdgeConv 2: 32 -> 64 (features from xcat[:,0:32))
    knn_kernel<32, 224><<<ROWS / 128, 128, 0, stream>>>(xcat, idx);
    edgeconv_kernel<32, 224, 64, 64>
        <<<dim3(ROWS / 4, 1), 256, 0, stream>>>(xcat, idx, W2, g2, b2, m2, v2, xcat, 32);

    // ---- EdgeConv 3: 64 -> 128 (features from xcat[:,32:96))
    knn_kernel<64, 224><<<ROWS / 128, 128, 0, stream>>>(xcat + 32, idx);
    edgeconv_kernel<64, 224, 128, 64>
        <<<dim3(ROWS / 4, 2), 256, 0, stream>>>(xcat + 32, idx, W3, g3, b3, m3, v3, xcat, 96);

    // ---- conv_global (224->256) + max over N  (idx dead; part aliases it)
    convglobal_kernel<<<BATCH * 128, 256, 0, stream>>>(
        xcat, Wg, gg, bg, mg, vg, part);
    reduce_gfeat_kernel<<<BATCH, 256, 0, stream>>>(part, gft, out + 776);

    // ---- heads
    heads_kernel<<<BATCH, 256, 0, stream>>>(
        gft, Wv1, bv1, Wv2, bv2, Wq1, bq1, Wq2, bq2, out);
}

// Round 7
// 4498.249 us; speedup vs baseline: 2.2979x; 2.2979x over previous
//
#include <hip/hip_runtime.h>
#include <hip/hip_bf16.h>

// ---------------------------------------------------------------------------
// BasicDGCNN forward, MI355X (gfx950). Inputs f32, output f32.
// Output layout (f32, flat): [0,768) vertex | [768,772) num_vertices |
// [772,776) nvs | [776,1800) gfeat | [1800,..) x_concat [4,8192,224].
//
// Round-7 (perf): (1) KNN split 8-way over j (grid 256x8 -> 4096 waves, was
// 512) with per-split top-21 candidates stashed in the not-yet-written
// channels of x_concat (row-local scratch @ f32 offset 96); merge kernel
// recomputes distances with bitwise-identical fma ordering and re-selects
// top-21 stably. Norms from global f4 (the old LDS-norm read pattern was a
// 64-way bank conflict: 3.1e7 SQ_LDS_BANK_CONFLICT). (2) EdgeConv rewritten:
// coalesced f4 staging of (x_j - x_i) into LDS, W-row in registers, 4
// accumulators; VGPR 224 -> ~110.
// ws need = 1,310,720 B (idx; part/gft alias idx after dead) — proven safe.
// ---------------------------------------------------------------------------

#define NPTS 8192
#define BATCH 4
#define KNBR 20

// ===================== KNN phase A: per-split top-21 =======================
// grid (ROWS/128, S); block 128 threads; thread = query point; j-range
// [s*NPTS/S, (s+1)*NPTS/S) staged in TJ-row LDS tiles. dist = xxi+xxj-2dot,
// all sums ascending-c fma chains (bitwise-matched by the merge kernel).
// Candidates (21 u16, dist-sorted, ties j-ascending) -> xcat row scratch.
template <int D, int RS, int S, int TJ>
__global__ __launch_bounds__(128) void knn_part(
    const float* feat, float* xcat) {
    __shared__ float xj[TJ * D];
    __shared__ float xxj[TJ];
    const int JC = NPTS / S;

    int gi = blockIdx.x * 128 + threadIdx.x;
    int s  = blockIdx.y;
    int b  = gi >> 13;
    int ib = gi & (NPTS - 1);
    const float* fb = feat + (size_t)b * NPTS * RS;

    float xi[D];
    if (D % 4 == 0) {
        #pragma unroll
        for (int c4 = 0; c4 < D / 4; ++c4) {
            float4 v = *(const float4*)(fb + (size_t)ib * RS + 4 * c4);
            xi[4 * c4] = v.x; xi[4 * c4 + 1] = v.y;
            xi[4 * c4 + 2] = v.z; xi[4 * c4 + 3] = v.w;
        }
    } else {
        #pragma unroll
        for (int c = 0; c < D; ++c) xi[c] = fb[(size_t)ib * RS + c];
    }
    float xxi = 0.f;
    #pragma unroll
    for (int c = 0; c < D; ++c) xxi = fmaf(xi[c], xi[c], xxi);

    float dl[21];
    int   il[21];
    #pragma unroll
    for (int t = 0; t < 21; ++t) { dl[t] = __builtin_inff(); il[t] = 0; }

    for (int j0 = s * JC; j0 < (s + 1) * JC; j0 += TJ) {
        __syncthreads();                       // protect prior-iter reads
        if (D % 4 == 0) {
            for (int e = threadIdx.x; e < TJ * (D / 4); e += 128) {
                int r = e / (D / 4), c4 = e % (D / 4);
                float4 v = *(const float4*)(fb + (size_t)(j0 + r) * RS + 4 * c4);
                *(float4*)(xj + r * D + 4 * c4) = v;
            }
        } else {
            for (int e = threadIdx.x; e < TJ * D; e += 128) {
                int r = e / D, c = e % D;
                xj[e] = fb[(size_t)(j0 + r) * RS + c];
            }
        }
        // norms from GLOBAL (coalesced-ish f4; ascending-c fma chain ==
        // bitwise-identical to knn_merge's recompute)
        if (threadIdx.x < TJ) {
            const float* row = fb + (size_t)(j0 + threadIdx.x) * RS;
            float sm = 0.f;
            if (D % 4 == 0) {
                #pragma unroll
                for (int c4 = 0; c4 < D / 4; ++c4) {
                    float4 v = *(const float4*)(row + 4 * c4);
                    sm = fmaf(v.x, v.x, sm); sm = fmaf(v.y, v.y, sm);
                    sm = fmaf(v.z, v.z, sm); sm = fmaf(v.w, v.w, sm);
                }
            } else {
                #pragma unroll
                for (int c = 0; c < D; ++c) sm = fmaf(row[c], row[c], sm);
            }
            xxj[threadIdx.x] = sm;
        }
        __syncthreads();
        for (int jj = 0; jj < TJ; ++jj) {
            float dot = 0.f;
            #pragma unroll
            for (int c = 0; c < D; ++c) dot = fmaf(xi[c], xj[jj * D + c], dot);
            float d = __builtin_fmaf(-2.f, dot, xxi + xxj[jj]);
            if (d < dl[20]) {                  // strict: ties keep earlier j
                dl[20] = d; il[20] = j0 + jj;
                #pragma unroll
                for (int t = 20; t > 0; --t) {
                    if (dl[t] < dl[t - 1]) {
                        float td = dl[t]; dl[t] = dl[t - 1]; dl[t - 1] = td;
                        int   ti = il[t]; il[t] = il[t - 1]; il[t - 1] = ti;
                    }
                }
            }
        }
    }
    unsigned short* cp =
        (unsigned short*)(xcat + (size_t)gi * 224 + 96) + s * 21;
    #pragma unroll
    for (int t = 0; t < 21; ++t) cp[t] = (unsigned short)il[t];
}

// ===================== KNN phase B: merge S x 21 candidates ================
// Thread per point. Recompute d with the SAME fma ordering as knn_part;
// insert candidates in (split asc, stored rank) order with strict < ->
// global stability == jax top_k (lowest j wins ties). Drop entry 0 (self).
template <int D, int RS, int S>
__global__ __launch_bounds__(256) void knn_merge(
    const float* feat, const float* xcat, unsigned short* __restrict__ idxout) {
    int gi = blockIdx.x * 256 + threadIdx.x;
    int b  = gi >> 13;
    int ib = gi & (NPTS - 1);
    const float* fb = feat + (size_t)b * NPTS * RS;

    float xi[D];
    if (D % 4 == 0) {
        #pragma unroll
        for (int c4 = 0; c4 < D / 4; ++c4) {
            float4 v = *(const float4*)(fb + (size_t)ib * RS + 4 * c4);
            xi[4 * c4] = v.x; xi[4 * c4 + 1] = v.y;
            xi[4 * c4 + 2] = v.z; xi[4 * c4 + 3] = v.w;
        }
    } else {
        #pragma unroll
        for (int c = 0; c < D; ++c) xi[c] = fb[(size_t)ib * RS + c];
    }
    float xxi = 0.f;
    #pragma unroll
    for (int c = 0; c < D; ++c) xxi = fmaf(xi[c], xi[c], xxi);

    const unsigned short* cp =
        (const unsigned short*)(xcat + (size_t)gi * 224 + 96);

    float dl[21];
    int   il[21];
    #pragma unroll
    for (int t = 0; t < 21; ++t) { dl[t] = __builtin_inff(); il[t] = 0; }

    for (int t = 0; t < S * 21; ++t) {
        int j = ((int)cp[t]) & (NPTS - 1);
        const float* row = fb + (size_t)j * RS;
        float dot = 0.f, xx = 0.f;
        if (D % 4 == 0) {
            #pragma unroll
            for (int c4 = 0; c4 < D / 4; ++c4) {
                float4 v = *(const float4*)(row + 4 * c4);
                dot = fmaf(xi[4 * c4], v.x, dot);     xx = fmaf(v.x, v.x, xx);
                dot = fmaf(xi[4 * c4 + 1], v.y, dot); xx = fmaf(v.y, v.y, xx);
                dot = fmaf(xi[4 * c4 + 2], v.z, dot); xx = fmaf(v.z, v.z, xx);
                dot = fmaf(xi[4 * c4 + 3], v.w, dot); xx = fmaf(v.w, v.w, xx);
            }
        } else {
            #pragma unroll
            for (int c = 0; c < D; ++c) {
                float v = row[c];
                dot = fmaf(xi[c], v, dot);
                xx  = fmaf(v, v, xx);
            }
        }
        float d = __builtin_fmaf(-2.f, dot, xxi + xx);
        if (d < dl[20]) {
            dl[20] = d; il[20] = j;
            #pragma unroll
            for (int u = 20; u > 0; --u) {
                if (dl[u] < dl[u - 1]) {
                    float td = dl[u]; dl[u] = dl[u - 1]; dl[u - 1] = td;
                    int   ti = il[u]; il[u] = il[u - 1]; il[u - 1] = ti;
                }
            }
        }
    }
    unsigned short* op = idxout + (size_t)gi * KNBR;
    #pragma unroll
    for (int t = 1; t < 21; ++t) op[t - 1] = (unsigned short)il[t];
}

// ===================== EdgeConv (fused BN + leaky + max_k) =================
// Block: 256 thr = OTILE out-channels x P points. Staging: (x_j - x_i) for
// P*20 neighbors cooperatively (f4 coalesced) into LDS; W-row in REGISTERS;
// inner loop = 1 LDS broadcast + 1 fma, 4 accumulators. feat/outb may alias
// x_concat (disjoint channel ranges) -> no __restrict__ on them.
template <int CIN, int RS, int COUT, int OTILE, int P>
__global__ __launch_bounds__(256) void edgeconv_kernel(
    const float* feat, const unsigned short* __restrict__ knn,
    const float* __restrict__ W, const float* __restrict__ g,
    const float* __restrict__ beta, const float* __restrict__ mu,
    const float* __restrict__ var,
    float* outb, int concat_off) {
    __shared__ float diff[P][KNBR][CIN];
    __shared__ float xil[P][CIN];
    __shared__ unsigned short kidx[P * KNBR];
    __shared__ float sl[OTILE], bl[OTILE], ml[OTILE];

    int tid = threadIdx.x;
    int h   = blockIdx.y;
    int n0  = blockIdx.x * P;                 // P divides 8192 -> same batch
    int b   = n0 >> 13;
    const float* fbase = feat + ((size_t)b << 13) * RS;

    for (int e = tid; e < P * CIN; e += 256)
        xil[e / CIN][e % CIN] = feat[(size_t)(n0 + e / CIN) * RS + e % CIN];
    for (int e = tid; e < P * KNBR; e += 256)
        kidx[e] = knn[(size_t)(n0 + e / KNBR) * KNBR + e % KNBR] & (NPTS - 1);
    for (int e = tid; e < OTILE; e += 256) {
        int o = h * OTILE + e;
        sl[e] = g[o] * rsqrtf(var[o] + 1e-5f);
        bl[e] = beta[o];
        ml[e] = mu[o];
    }
    __syncthreads();

    if (CIN % 4 == 0) {
        for (int e = tid; e < P * KNBR * (CIN / 4); e += 256) {
            int r = e / (CIN / 4), c4 = e % (CIN / 4);
            int p = r / KNBR, k = r % KNBR;
            int j = (int)kidx[r];
            float4 v = *(const float4*)(fbase + (size_t)j * RS + 4 * c4);
            diff[p][k][4 * c4 + 0] = v.x - xil[p][4 * c4 + 0];
            diff[p][k][4 * c4 + 1] = v.y - xil[p][4 * c4 + 1];
            diff[p][k][4 * c4 + 2] = v.z - xil[p][4 * c4 + 2];
            diff[p][k][4 * c4 + 3] = v.w - xil[p][4 * c4 + 3];
        }
    } else {
        for (int e = tid; e < P * KNBR * CIN; e += 256) {
            int r = e / CIN, c = e % CIN;
            int p = r / KNBR, k = r % KNBR;
            int j = (int)kidx[r];
            diff[p][k][c] = fbase[(size_t)j * RS + c] - xil[p][c];
        }
    }
    __syncthreads();

    int ol = tid % OTILE, p = tid / OTILE;
    int o  = h * OTILE + ol;

    float wreg[CIN];
    #pragma unroll
    for (int c = 0; c < CIN; ++c) wreg[c] = W[(size_t)o * (2 * CIN) + c];
    float a = 0.f;
    #pragma unroll
    for (int c = 0; c < CIN; ++c) a = fmaf(wreg[c], xil[p][c], a);
    #pragma unroll
    for (int c = 0; c < CIN; ++c) wreg[c] = W[(size_t)o * (2 * CIN) + CIN + c];

    float s = sl[ol], mm = ml[ol], bb = bl[ol];
    float best = -__builtin_inff();
    for (int k = 0; k < KNBR; ++k) {
        float ac0 = a, ac1 = 0.f, ac2 = 0.f, ac3 = 0.f;
        #pragma unroll
        for (int c = 0; c < CIN; ++c) {
            float d = diff[p][k][c];
            if ((c & 3) == 0)      ac0 = fmaf(wreg[c], d, ac0);
            else if ((c & 3) == 1) ac1 = fmaf(wreg[c], d, ac1);
            else if ((c & 3) == 2) ac2 = fmaf(wreg[c], d, ac2);
            else                   ac3 = fmaf(wreg[c], d, ac3);
        }
        float acc = ((ac0 + ac1) + ac2) + ac3;
        float y = (acc - mm) * s + bb;
        y = (y >= 0.f) ? y : 0.2f * y;
        best = fmaxf(best, y);
    }
    outb[(size_t)(n0 + p) * 224 + concat_off + o] = best;
}

// ===================== conv_global + partial max over N ====================
__global__ __launch_bounds__(256) void convglobal_kernel(
    const float* __restrict__ xcat,
    const float* __restrict__ Wg, const float* __restrict__ gg,
    const float* __restrict__ bg, const float* __restrict__ mg,
    const float* __restrict__ vg,
    float* __restrict__ partial) {
    int o     = threadIdx.x;
    int chunk = blockIdx.x & 127;
    int b     = blockIdx.x >> 7;

    float s  = gg[o] * rsqrtf(vg[o] + 1e-5f);
    float mm = mg[o], bb = bg[o];
    const float* wrow = Wg + (size_t)o * 224;

    float best = -__builtin_inff();
    for (int grp = 0; grp < 2; ++grp) {
        int n0 = b * NPTS + chunk * 64 + grp * 32;
        float acc[32];
        #pragma unroll
        for (int p = 0; p < 32; ++p) acc[p] = 0.f;
        for (int c = 0; c < 224; ++c) {
            float w = wrow[c];
            const float* f = xcat + (size_t)n0 * 224 + c;
            #pragma unroll
            for (int p = 0; p < 32; ++p) acc[p] = fmaf(w, f[p * 224], acc[p]);
        }
        #pragma unroll
        for (int p = 0; p < 32; ++p) {
            float y = (acc[p] - mm) * s + bb;
            y = (y >= 0.f) ? y : 0.2f * y;
            best = fmaxf(best, y);
        }
    }
    partial[(size_t)blockIdx.x * 256 + o] = best;
}

__global__ void reduce_gfeat_kernel(const float* __restrict__ partial,
                                    float* __restrict__ gfeat,
                                    float* __restrict__ outg) {
    int b = blockIdx.x, o = threadIdx.x;
    float best = -__builtin_inff();
    for (int ch = 0; ch < 128; ++ch)
        best = fmaxf(best, partial[((size_t)b * 128 + ch) * 256 + o]);
    gfeat[b * 256 + o] = best;
    outg[b * 256 + o]  = best;
}

// ===================== heads (per-batch block) =============================
__global__ __launch_bounds__(256) void heads_kernel(
    const float* __restrict__ gfeat,
    const float* __restrict__ Wv1, const float* __restrict__ bv1,
    const float* __restrict__ Wv2, const float* __restrict__ bv2,
    const float* __restrict__ Wq1, const float* __restrict__ bq1,
    const float* __restrict__ Wq2, const float* __restrict__ bq2,
    float* __restrict__ out) {
    int b = blockIdx.x, t = threadIdx.x;
    __shared__ float gf[256], h[512], q[64];
    gf[t] = gfeat[b * 256 + t];
    __syncthreads();
    for (int r = t; r < 512; r += 256) {
        float acc = bv1[r];
        for (int c = 0; c < 256; ++c) acc = fmaf(Wv1[r * 256 + c], gf[c], acc);
        h[r] = fmaxf(acc, 0.f);
    }
    __syncthreads();
    if (t < 192) {
        float acc = bv2[t];
        for (int c = 0; c < 512; ++c) acc = fmaf(Wv2[t * 512 + c], h[c], acc);
        out[b * 192 + t] = acc;               // vertex_coords
    } else {
        int r = t - 192;
        if (r < 64) {
            float acc = bq1[r];
            for (int c = 0; c < 256; ++c) acc = fmaf(Wq1[r * 256 + c], gf[c], acc);
            q[r] = fmaxf(acc, 0.f);
        }
    }
    __syncthreads();
    if (t == 0) {
        float acc = bq2[0];
        for (int c = 0; c < 64; ++c) acc = fmaf(Wq2[c], q[c], acc);
        float nv = 1.0f / (1.0f + expf(-acc));
        out[772 + b] = nv;                                       // nvs
        float num = fminf(fmaxf(rintf(nv * 64.0f), 1.0f), 64.0f);
        out[768 + b] = num;                                      // num_vertices
    }
}

// ============================== launch =====================================
extern "C" void kernel_launch(void* const* d_in, const int* in_sizes, int n_in,
                              void* d_out, int out_size, void* d_ws, size_t ws_size,
                              hipStream_t stream) {
    (void)in_sizes; (void)n_in; (void)out_size; (void)ws_size;
    const float* x   = (const float*)d_in[0];
    const float* W1  = (const float*)d_in[1];
    const float* g1  = (const float*)d_in[2];
    const float* b1  = (const float*)d_in[3];
    const float* m1  = (const float*)d_in[4];
    const float* v1  = (const float*)d_in[5];
    const float* W2  = (const float*)d_in[6];
    const float* g2  = (const float*)d_in[7];
    const float* b2  = (const float*)d_in[8];
    const float* m2  = (const float*)d_in[9];
    const float* v2  = (const float*)d_in[10];
    const float* W3  = (const float*)d_in[11];
    const float* g3  = (const float*)d_in[12];
    const float* b3  = (const float*)d_in[13];
    const float* m3  = (const float*)d_in[14];
    const float* v3  = (const float*)d_in[15];
    const float* Wg  = (const float*)d_in[16];
    const float* gg  = (const float*)d_in[17];
    const float* bg  = (const float*)d_in[18];
    const float* mg  = (const float*)d_in[19];
    const float* vg  = (const float*)d_in[20];
    const float* Wv1 = (const float*)d_in[21];
    const float* bv1 = (const float*)d_in[22];
    const float* Wv2 = (const float*)d_in[23];
    const float* bv2 = (const float*)d_in[24];
    const float* Wq1 = (const float*)d_in[25];
    const float* bq1 = (const float*)d_in[26];
    const float* Wq2 = (const float*)d_in[27];
    const float* bq2 = (const float*)d_in[28];

    float* out  = (float*)d_out;
    float* xcat = out + 1800;                    // f32 [4,8192,224]
    char* ws = (char*)d_ws;
    const int ROWS = BATCH * NPTS;   // 32768

    // ws layout (1,310,720 B; part/gft alias idx AFTER it is dead):
    unsigned short* idx  = (unsigned short*)(ws);        // [32768,20] u16
    float*          part = (float*)(ws);                 // [512,256] f32 (alias)
    float*          gft  = (float*)(ws + 524288);        // [4,256]   f32 (alias)

    // ---- EdgeConv 1: 5 -> 32
    knn_part<5, 5, 8, 128><<<dim3(ROWS / 128, 8), 128, 0, stream>>>(x, xcat);
    knn_merge<5, 5, 8><<<ROWS / 256, 256, 0, stream>>>(x, xcat, idx);
    edgeconv_kernel<5, 5, 32, 32, 8>
        <<<dim3(ROWS / 8, 1), 256, 0, stream>>>(x, idx, W1, g1, b1, m1, v1, xcat, 0);

    // ---- EdgeConv 2: 32 -> 64 (features from xcat[:,0:32))
    knn_part<32, 224, 8, 128><<<dim3(ROWS / 128, 8), 128, 0, stream>>>(xcat, xcat);
    knn_merge<32, 224, 8><<<ROWS / 256, 256, 0, stream>>>(xcat, xcat, idx);
    edgeconv_kernel<32, 224, 64, 64, 4>
        <<<dim3(ROWS / 4, 1), 256, 0, stream>>>(xcat, idx, W2, g2, b2, m2, v2, xcat, 32);

    // ---- EdgeConv 3: 64 -> 128 (features from xcat[:,32:96))
    knn_part<64, 224, 8, 64><<<dim3(ROWS / 128, 8), 128, 0, stream>>>(xcat + 32, xcat);
    knn_merge<64, 224, 8><<<ROWS / 256, 256, 0, stream>>>(xcat + 32, xcat, idx);
    edgeconv_kernel<64, 224, 128, 64, 4>
        <<<dim3(ROWS / 4, 2), 256, 0, stream>>>(xcat + 32, idx, W3, g3, b3, m3, v3, xcat, 96);

    // ---- conv_global (224->256) + max over N  (idx dead; part aliases it)
    convglobal_kernel<<<BATCH * 128, 256, 0, stream>>>(
        xcat, Wg, gg, bg, mg, vg, part);
    reduce_gfeat_kernel<<<BATCH, 256, 0, stream>>>(part, gft, out + 776);

    // ---- heads
    heads_kernel<<<BATCH, 256, 0, stream>>>(
        gft, Wv1, bv1, Wv2, bv2, Wq1, bq1, Wq2, bq2, out);
}

// Round 8
// 4369.076 us; speedup vs baseline: 2.3659x; 1.0296x over previous
//
#include <hip/hip_runtime.h>
#include <hip/hip_bf16.h>

// ---------------------------------------------------------------------------
// BasicDGCNN forward, MI355X (gfx950). Inputs f32, output f32.
// Output layout (f32, flat): [0,768) vertex | [768,772) num_vertices |
// [772,776) nvs | [776,1800) gfeat | [1800,..) x_concat [4,8192,224].
//
// Round-8 (perf): (1) knn_part inner loop reads xj as float4 (ds_read_b128,
// wave-broadcast, conflict-free) with UNCHANGED ascending-c fma chain ->
// ~128 -> ~80 issue slots per (i,j) pair. (2) convglobal rewritten as an
// LDS-tiled GEMM (it was latency-strangled: per-lane 896B-stride W gathers +
// 14k serialized scalar feature loads, VALUBusy 5%): 64pt x 64ch tiles,
// K-chunks of 56, both tiles stored c-major so inner loop = 2 conflict-free
// b128 reads + 16 fma (4o x 4p register tile), fused BN+leaky+max.
// ws need = 1,310,720 B (idx; part/gft alias idx after dead) — proven safe.
// ---------------------------------------------------------------------------

#define NPTS 8192
#define BATCH 4
#define KNBR 20

// ===================== KNN phase A: per-split top-21 =======================
// grid (ROWS/128, S); block 128 threads; thread = query point; j-range
// [s*NPTS/S, (s+1)*NPTS/S) staged in TJ-row LDS tiles. dist = xxi+xxj-2dot,
// ascending-c fma chains (bitwise-matched by the merge kernel).
// Candidates (21 u16, dist-sorted, ties j-ascending) -> xcat row scratch.
template <int D, int RS, int S, int TJ>
__global__ __launch_bounds__(128) void knn_part(
    const float* feat, float* xcat) {
    __shared__ float xj[TJ * D];
    __shared__ float xxj[TJ];
    const int JC = NPTS / S;

    int gi = blockIdx.x * 128 + threadIdx.x;
    int s  = blockIdx.y;
    int b  = gi >> 13;
    int ib = gi & (NPTS - 1);
    const float* fb = feat + (size_t)b * NPTS * RS;

    float xi[D];
    if (D % 4 == 0) {
        #pragma unroll
        for (int c4 = 0; c4 < D / 4; ++c4) {
            float4 v = *(const float4*)(fb + (size_t)ib * RS + 4 * c4);
            xi[4 * c4] = v.x; xi[4 * c4 + 1] = v.y;
            xi[4 * c4 + 2] = v.z; xi[4 * c4 + 3] = v.w;
        }
    } else {
        #pragma unroll
        for (int c = 0; c < D; ++c) xi[c] = fb[(size_t)ib * RS + c];
    }
    float xxi = 0.f;
    #pragma unroll
    for (int c = 0; c < D; ++c) xxi = fmaf(xi[c], xi[c], xxi);

    float dl[21];
    int   il[21];
    #pragma unroll
    for (int t = 0; t < 21; ++t) { dl[t] = __builtin_inff(); il[t] = 0; }

    for (int j0 = s * JC; j0 < (s + 1) * JC; j0 += TJ) {
        __syncthreads();                       // protect prior-iter reads
        if (D % 4 == 0) {
            for (int e = threadIdx.x; e < TJ * (D / 4); e += 128) {
                int r = e / (D / 4), c4 = e % (D / 4);
                float4 v = *(const float4*)(fb + (size_t)(j0 + r) * RS + 4 * c4);
                *(float4*)(xj + r * D + 4 * c4) = v;
            }
        } else {
            for (int e = threadIdx.x; e < TJ * D; e += 128) {
                int r = e / D, c = e % D;
                xj[e] = fb[(size_t)(j0 + r) * RS + c];
            }
        }
        // norms from GLOBAL (ascending-c fma chain == knn_merge's recompute)
        if (threadIdx.x < TJ) {
            const float* row = fb + (size_t)(j0 + threadIdx.x) * RS;
            float sm = 0.f;
            if (D % 4 == 0) {
                #pragma unroll
                for (int c4 = 0; c4 < D / 4; ++c4) {
                    float4 v = *(const float4*)(row + 4 * c4);
                    sm = fmaf(v.x, v.x, sm); sm = fmaf(v.y, v.y, sm);
                    sm = fmaf(v.z, v.z, sm); sm = fmaf(v.w, v.w, sm);
                }
            } else {
                #pragma unroll
                for (int c = 0; c < D; ++c) sm = fmaf(row[c], row[c], sm);
            }
            xxj[threadIdx.x] = sm;
        }
        __syncthreads();
        for (int jj = 0; jj < TJ; ++jj) {
            float dot = 0.f;
            if (D % 4 == 0) {
                const float* xr = xj + jj * D;
                #pragma unroll
                for (int c4 = 0; c4 < D / 4; ++c4) {   // b128 broadcast reads
                    float4 v = *(const float4*)(xr + 4 * c4);
                    dot = fmaf(xi[4 * c4 + 0], v.x, dot);
                    dot = fmaf(xi[4 * c4 + 1], v.y, dot);
                    dot = fmaf(xi[4 * c4 + 2], v.z, dot);
                    dot = fmaf(xi[4 * c4 + 3], v.w, dot);
                }
            } else {
                #pragma unroll
                for (int c = 0; c < D; ++c) dot = fmaf(xi[c], xj[jj * D + c], dot);
            }
            float d = __builtin_fmaf(-2.f, dot, xxi + xxj[jj]);
            if (d < dl[20]) {                  // strict: ties keep earlier j
                dl[20] = d; il[20] = j0 + jj;
                #pragma unroll
                for (int t = 20; t > 0; --t) {
                    if (dl[t] < dl[t - 1]) {
                        float td = dl[t]; dl[t] = dl[t - 1]; dl[t - 1] = td;
                        int   ti = il[t]; il[t] = il[t - 1]; il[t - 1] = ti;
                    }
                }
            }
        }
    }
    unsigned short* cp =
        (unsigned short*)(xcat + (size_t)gi * 224 + 96) + s * 21;
    #pragma unroll
    for (int t = 0; t < 21; ++t) cp[t] = (unsigned short)il[t];
}

// ===================== KNN phase B: merge S x 21 candidates ================
template <int D, int RS, int S>
__global__ __launch_bounds__(256) void knn_merge(
    const float* feat, const float* xcat, unsigned short* __restrict__ idxout) {
    int gi = blockIdx.x * 256 + threadIdx.x;
    int b  = gi >> 13;
    int ib = gi & (NPTS - 1);
    const float* fb = feat + (size_t)b * NPTS * RS;

    float xi[D];
    if (D % 4 == 0) {
        #pragma unroll
        for (int c4 = 0; c4 < D / 4; ++c4) {
            float4 v = *(const float4*)(fb + (size_t)ib * RS + 4 * c4);
            xi[4 * c4] = v.x; xi[4 * c4 + 1] = v.y;
            xi[4 * c4 + 2] = v.z; xi[4 * c4 + 3] = v.w;
        }
    } else {
        #pragma unroll
        for (int c = 0; c < D; ++c) xi[c] = fb[(size_t)ib * RS + c];
    }
    float xxi = 0.f;
    #pragma unroll
    for (int c = 0; c < D; ++c) xxi = fmaf(xi[c], xi[c], xxi);

    const unsigned short* cp =
        (const unsigned short*)(xcat + (size_t)gi * 224 + 96);

    float dl[21];
    int   il[21];
    #pragma unroll
    for (int t = 0; t < 21; ++t) { dl[t] = __builtin_inff(); il[t] = 0; }

    for (int t = 0; t < S * 21; ++t) {
        int j = ((int)cp[t]) & (NPTS - 1);
        const float* row = fb + (size_t)j * RS;
        float dot = 0.f, xx = 0.f;
        if (D % 4 == 0) {
            #pragma unroll
            for (int c4 = 0; c4 < D / 4; ++c4) {
                float4 v = *(const float4*)(row + 4 * c4);
                dot = fmaf(xi[4 * c4], v.x, dot);     xx = fmaf(v.x, v.x, xx);
                dot = fmaf(xi[4 * c4 + 1], v.y, dot); xx = fmaf(v.y, v.y, xx);
                dot = fmaf(xi[4 * c4 + 2], v.z, dot); xx = fmaf(v.z, v.z, xx);
                dot = fmaf(xi[4 * c4 + 3], v.w, dot); xx = fmaf(v.w, v.w, xx);
            }
        } else {
            #pragma unroll
            for (int c = 0; c < D; ++c) {
                float v = row[c];
                dot = fmaf(xi[c], v, dot);
                xx  = fmaf(v, v, xx);
            }
        }
        float d = __builtin_fmaf(-2.f, dot, xxi + xx);
        if (d < dl[20]) {
            dl[20] = d; il[20] = j;
            #pragma unroll
            for (int u = 20; u > 0; --u) {
                if (dl[u] < dl[u - 1]) {
                    float td = dl[u]; dl[u] = dl[u - 1]; dl[u - 1] = td;
                    int   ti = il[u]; il[u] = il[u - 1]; il[u - 1] = ti;
                }
            }
        }
    }
    unsigned short* op = idxout + (size_t)gi * KNBR;
    #pragma unroll
    for (int t = 1; t < 21; ++t) op[t - 1] = (unsigned short)il[t];
}

// ===================== EdgeConv (fused BN + leaky + max_k) =================
template <int CIN, int RS, int COUT, int OTILE, int P>
__global__ __launch_bounds__(256) void edgeconv_kernel(
    const float* feat, const unsigned short* __restrict__ knn,
    const float* __restrict__ W, const float* __restrict__ g,
    const float* __restrict__ beta, const float* __restrict__ mu,
    const float* __restrict__ var,
    float* outb, int concat_off) {
    __shared__ float diff[P][KNBR][CIN];
    __shared__ float xil[P][CIN];
    __shared__ unsigned short kidx[P * KNBR];
    __shared__ float sl[OTILE], bl[OTILE], ml[OTILE];

    int tid = threadIdx.x;
    int h   = blockIdx.y;
    int n0  = blockIdx.x * P;                 // P divides 8192 -> same batch
    int b   = n0 >> 13;
    const float* fbase = feat + ((size_t)b << 13) * RS;

    for (int e = tid; e < P * CIN; e += 256)
        xil[e / CIN][e % CIN] = feat[(size_t)(n0 + e / CIN) * RS + e % CIN];
    for (int e = tid; e < P * KNBR; e += 256)
        kidx[e] = knn[(size_t)(n0 + e / KNBR) * KNBR + e % KNBR] & (NPTS - 1);
    for (int e = tid; e < OTILE; e += 256) {
        int o = h * OTILE + e;
        sl[e] = g[o] * rsqrtf(var[o] + 1e-5f);
        bl[e] = beta[o];
        ml[e] = mu[o];
    }
    __syncthreads();

    if (CIN % 4 == 0) {
        for (int e = tid; e < P * KNBR * (CIN / 4); e += 256) {
            int r = e / (CIN / 4), c4 = e % (CIN / 4);
            int p = r / KNBR, k = r % KNBR;
            int j = (int)kidx[r];
            float4 v = *(const float4*)(fbase + (size_t)j * RS + 4 * c4);
            diff[p][k][4 * c4 + 0] = v.x - xil[p][4 * c4 + 0];
            diff[p][k][4 * c4 + 1] = v.y - xil[p][4 * c4 + 1];
            diff[p][k][4 * c4 + 2] = v.z - xil[p][4 * c4 + 2];
            diff[p][k][4 * c4 + 3] = v.w - xil[p][4 * c4 + 3];
        }
    } else {
        for (int e = tid; e < P * KNBR * CIN; e += 256) {
            int r = e / CIN, c = e % CIN;
            int p = r / CIN == 0 ? 0 : 0;  // (unused placeholder removed below)
            int pp = r / KNBR, k = r % KNBR;
            int j = (int)kidx[r];
            diff[pp][k][c] = fbase[(size_t)j * RS + c] - xil[pp][c];
        }
    }
    __syncthreads();

    int ol = tid % OTILE, p = tid / OTILE;
    int o  = h * OTILE + ol;

    float wreg[CIN];
    #pragma unroll
    for (int c = 0; c < CIN; ++c) wreg[c] = W[(size_t)o * (2 * CIN) + c];
    float a = 0.f;
    #pragma unroll
    for (int c = 0; c < CIN; ++c) a = fmaf(wreg[c], xil[p][c], a);
    #pragma unroll
    for (int c = 0; c < CIN; ++c) wreg[c] = W[(size_t)o * (2 * CIN) + CIN + c];

    float s = sl[ol], mm = ml[ol], bb = bl[ol];
    float best = -__builtin_inff();
    for (int k = 0; k < KNBR; ++k) {
        float ac0 = a, ac1 = 0.f, ac2 = 0.f, ac3 = 0.f;
        #pragma unroll
        for (int c = 0; c < CIN; ++c) {
            float d = diff[p][k][c];
            if ((c & 3) == 0)      ac0 = fmaf(wreg[c], d, ac0);
            else if ((c & 3) == 1) ac1 = fmaf(wreg[c], d, ac1);
            else if ((c & 3) == 2) ac2 = fmaf(wreg[c], d, ac2);
            else                   ac3 = fmaf(wreg[c], d, ac3);
        }
        float acc = ((ac0 + ac1) + ac2) + ac3;
        float y = (acc - mm) * s + bb;
        y = (y >= 0.f) ? y : 0.2f * y;
        best = fmaxf(best, y);
    }
    outb[(size_t)(n0 + p) * 224 + concat_off + o] = best;
}

// ===================== conv_global: LDS-tiled GEMM + fused max =============
// grid (512 pchunks, 4 otiles); block 256 thr = 16(oi) x 16(pi); each thread
// a 4o x 4p register tile. K staged in chunks of 56, BOTH tiles c-major
// (flT[c][p], WlT[c][o]) so inner loop = 2 conflict-free ds_read_b128 +
// 16 fma. Fused BN + leaky + max over the block's 64 points via LDS reduce.
__global__ __launch_bounds__(256) void convglobal_kernel(
    const float* __restrict__ xcat,
    const float* __restrict__ Wg, const float* __restrict__ gg,
    const float* __restrict__ bg, const float* __restrict__ mg,
    const float* __restrict__ vg,
    float* __restrict__ partial) {
    const int KC = 56, PT = 64, OT = 64, ST = 68;   // ST: padded row stride
    __shared__ float flT[KC * ST];                  // [c][p]  15.2 KB
    __shared__ float WlT[KC * ST];                  // [c][o]  15.2 KB
    __shared__ float red[64 * 17];                  //          4.4 KB

    int tid = threadIdx.x;
    int oi  = tid & 15, pi = tid >> 4;
    int o0  = blockIdx.y * OT;
    int n0  = blockIdx.x * PT;                      // 64 | 8192 -> same batch
    int b   = n0 >> 13;
    int pchunk = blockIdx.x & 127;                  // chunk within batch

    float acc[4][4];
    #pragma unroll
    for (int u = 0; u < 4; ++u)
        #pragma unroll
        for (int v = 0; v < 4; ++v) acc[u][v] = 0.f;

    for (int kc = 0; kc < 224; kc += KC) {
        __syncthreads();
        // stage feature tile transposed: read f4 along c, scatter to flT[c][p]
        for (int e = tid; e < PT * (KC / 4); e += 256) {
            int p = e / (KC / 4), c4 = e % (KC / 4);
            float4 v = *(const float4*)(xcat + (size_t)(n0 + p) * 224 + kc + 4 * c4);
            flT[(4 * c4 + 0) * ST + p] = v.x;
            flT[(4 * c4 + 1) * ST + p] = v.y;
            flT[(4 * c4 + 2) * ST + p] = v.z;
            flT[(4 * c4 + 3) * ST + p] = v.w;
        }
        // stage W tile transposed: WlT[c][o]
        for (int e = tid; e < OT * (KC / 4); e += 256) {
            int o = e / (KC / 4), c4 = e % (KC / 4);
            float4 v = *(const float4*)(Wg + (size_t)(o0 + o) * 224 + kc + 4 * c4);
            WlT[(4 * c4 + 0) * ST + o] = v.x;
            WlT[(4 * c4 + 1) * ST + o] = v.y;
            WlT[(4 * c4 + 2) * ST + o] = v.z;
            WlT[(4 * c4 + 3) * ST + o] = v.w;
        }
        __syncthreads();
        #pragma unroll 8
        for (int c = 0; c < KC; ++c) {
            float4 w4 = *(const float4*)(WlT + c * ST + oi * 4);
            float4 f4 = *(const float4*)(flT + c * ST + pi * 4);
            acc[0][0] = fmaf(w4.x, f4.x, acc[0][0]);
            acc[0][1] = fmaf(w4.x, f4.y, acc[0][1]);
            acc[0][2] = fmaf(w4.x, f4.z, acc[0][2]);
            acc[0][3] = fmaf(w4.x, f4.w, acc[0][3]);
            acc[1][0] = fmaf(w4.y, f4.x, acc[1][0]);
            acc[1][1] = fmaf(w4.y, f4.y, acc[1][1]);
            acc[1][2] = fmaf(w4.y, f4.z, acc[1][2]);
            acc[1][3] = fmaf(w4.y, f4.w, acc[1][3]);
            acc[2][0] = fmaf(w4.z, f4.x, acc[2][0]);
            acc[2][1] = fmaf(w4.z, f4.y, acc[2][1]);
            acc[2][2] = fmaf(w4.z, f4.z, acc[2][2]);
            acc[2][3] = fmaf(w4.z, f4.w, acc[2][3]);
            acc[3][0] = fmaf(w4.w, f4.x, acc[3][0]);
            acc[3][1] = fmaf(w4.w, f4.y, acc[3][1]);
            acc[3][2] = fmaf(w4.w, f4.z, acc[3][2]);
            acc[3][3] = fmaf(w4.w, f4.w, acc[3][3]);
        }
    }
    // epilogue: BN + leaky + max over this thread's 4 points -> LDS reduce
    #pragma unroll
    for (int u = 0; u < 4; ++u) {
        int oL = oi * 4 + u, o = o0 + oL;
        float s = gg[o] * rsqrtf(vg[o] + 1e-5f);
        float mm = mg[o], bb = bg[o];
        float best = -__builtin_inff();
        #pragma unroll
        for (int v = 0; v < 4; ++v) {
            float y = (acc[u][v] - mm) * s + bb;
            y = (y >= 0.f) ? y : 0.2f * y;
            best = fmaxf(best, y);
        }
        red[oL * 17 + pi] = best;
    }
    __syncthreads();
    if (tid < 64) {
        float best = -__builtin_inff();
        #pragma unroll
        for (int q = 0; q < 16; ++q) best = fmaxf(best, red[tid * 17 + q]);
        partial[((size_t)(b * 128 + pchunk)) * 256 + o0 + tid] = best;
    }
}

__global__ void reduce_gfeat_kernel(const float* __restrict__ partial,
                                    float* __restrict__ gfeat,
                                    float* __restrict__ outg) {
    int b = blockIdx.x, o = threadIdx.x;
    float best = -__builtin_inff();
    for (int ch = 0; ch < 128; ++ch)
        best = fmaxf(best, partial[((size_t)b * 128 + ch) * 256 + o]);
    gfeat[b * 256 + o] = best;
    outg[b * 256 + o]  = best;
}

// ===================== heads (per-batch block) =============================
__global__ __launch_bounds__(256) void heads_kernel(
    const float* __restrict__ gfeat,
    const float* __restrict__ Wv1, const float* __restrict__ bv1,
    const float* __restrict__ Wv2, const float* __restrict__ bv2,
    const float* __restrict__ Wq1, const float* __restrict__ bq1,
    const float* __restrict__ Wq2, const float* __restrict__ bq2,
    float* __restrict__ out) {
    int b = blockIdx.x, t = threadIdx.x;
    __shared__ float gf[256], h[512], q[64];
    gf[t] = gfeat[b * 256 + t];
    __syncthreads();
    for (int r = t; r < 512; r += 256) {
        float acc = bv1[r];
        for (int c = 0; c < 256; ++c) acc = fmaf(Wv1[r * 256 + c], gf[c], acc);
        h[r] = fmaxf(acc, 0.f);
    }
    __syncthreads();
    if (t < 192) {
        float acc = bv2[t];
        for (int c = 0; c < 512; ++c) acc = fmaf(Wv2[t * 512 + c], h[c], acc);
        out[b * 192 + t] = acc;               // vertex_coords
    } else {
        int r = t - 192;
        if (r < 64) {
            float acc = bq1[r];
            for (int c = 0; c < 256; ++c) acc = fmaf(Wq1[r * 256 + c], gf[c], acc);
            q[r] = fmaxf(acc, 0.f);
        }
    }
    __syncthreads();
    if (t == 0) {
        float acc = bq2[0];
        for (int c = 0; c < 64; ++c) acc = fmaf(Wq2[c], q[c], acc);
        float nv = 1.0f / (1.0f + expf(-acc));
        out[772 + b] = nv;                                       // nvs
        float num = fminf(fmaxf(rintf(nv * 64.0f), 1.0f), 64.0f);
        out[768 + b] = num;                                      // num_vertices
    }
}

// ============================== launch =====================================
extern "C" void kernel_launch(void* const* d_in, const int* in_sizes, int n_in,
                              void* d_out, int out_size, void* d_ws, size_t ws_size,
                              hipStream_t stream) {
    (void)in_sizes; (void)n_in; (void)out_size; (void)ws_size;
    const float* x   = (const float*)d_in[0];
    const float* W1  = (const float*)d_in[1];
    const float* g1  = (const float*)d_in[2];
    const float* b1  = (const float*)d_in[3];
    const float* m1  = (const float*)d_in[4];
    const float* v1  = (const float*)d_in[5];
    const float* W2  = (const float*)d_in[6];
    const float* g2  = (const float*)d_in[7];
    const float* b2  = (const float*)d_in[8];
    const float* m2  = (const float*)d_in[9];
    const float* v2  = (const float*)d_in[10];
    const float* W3  = (const float*)d_in[11];
    const float* g3  = (const float*)d_in[12];
    const float* b3  = (const float*)d_in[13];
    const float* m3  = (const float*)d_in[14];
    const float* v3  = (const float*)d_in[15];
    const float* Wg  = (const float*)d_in[16];
    const float* gg  = (const float*)d_in[17];
    const float* bg  = (const float*)d_in[18];
    const float* mg  = (const float*)d_in[19];
    const float* vg  = (const float*)d_in[20];
    const float* Wv1 = (const float*)d_in[21];
    const float* bv1 = (const float*)d_in[22];
    const float* Wv2 = (const float*)d_in[23];
    const float* bv2 = (const float*)d_in[24];
    const float* Wq1 = (const float*)d_in[25];
    const float* bq1 = (const float*)d_in[26];
    const float* Wq2 = (const float*)d_in[27];
    const float* bq2 = (const float*)d_in[28];

    float* out  = (float*)d_out;
    float* xcat = out + 1800;                    // f32 [4,8192,224]
    char* ws = (char*)d_ws;
    const int ROWS = BATCH * NPTS;   // 32768

    // ws layout (1,310,720 B; part/gft alias idx AFTER it is dead):
    unsigned short* idx  = (unsigned short*)(ws);        // [32768,20] u16
    float*          part = (float*)(ws);                 // [512,256] f32 (alias)
    float*          gft  = (float*)(ws + 524288);        // [4,256]   f32 (alias)

    // ---- EdgeConv 1: 5 -> 32
    knn_part<5, 5, 8, 128><<<dim3(ROWS / 128, 8), 128, 0, stream>>>(x, xcat);
    knn_merge<5, 5, 8><<<ROWS / 256, 256, 0, stream>>>(x, xcat, idx);
    edgeconv_kernel<5, 5, 32, 32, 8>
        <<<dim3(ROWS / 8, 1), 256, 0, stream>>>(x, idx, W1, g1, b1, m1, v1, xcat, 0);

    // ---- EdgeConv 2: 32 -> 64 (features from xcat[:,0:32))
    knn_part<32, 224, 8, 128><<<dim3(ROWS / 128, 8), 128, 0, stream>>>(xcat, xcat);
    knn_merge<32, 224, 8><<<ROWS / 256, 256, 0, stream>>>(xcat, xcat, idx);
    edgeconv_kernel<32, 224, 64, 64, 4>
        <<<dim3(ROWS / 4, 1), 256, 0, stream>>>(xcat, idx, W2, g2, b2, m2, v2, xcat, 32);

    // ---- EdgeConv 3: 64 -> 128 (features from xcat[:,32:96))
    knn_part<64, 224, 8, 64><<<dim3(ROWS / 128, 8), 128, 0, stream>>>(xcat + 32, xcat);
    knn_merge<64, 224, 8><<<ROWS / 256, 256, 0, stream>>>(xcat + 32, xcat, idx);
    edgeconv_kernel<64, 224, 128, 64, 4>
        <<<dim3(ROWS / 4, 2), 256, 0, stream>>>(xcat + 32, idx, W3, g3, b3, m3, v3, xcat, 96);

    // ---- conv_global (224->256) + max over N  (idx dead; part aliases it)
    convglobal_kernel<<<dim3(ROWS / 64, 4), 256, 0, stream>>>(
        xcat, Wg, gg, bg, mg, vg, part);
    reduce_gfeat_kernel<<<BATCH, 256, 0, stream>>>(part, gft, out + 776);

    // ---- heads
    heads_kernel<<<BATCH, 256, 0, stream>>>(
        gft, Wv1, bv1, Wv2, bv2, Wq1, bq1, Wq2, bq2, out);
}